// Round 4
// baseline (315.213 us; speedup 1.0000x reference)
//
#include <hip/hip_runtime.h>

// ---------- types ----------
using bf16x8 = __attribute__((ext_vector_type(8))) short;           // 8 bf16 (4 VGPR)
using u16x8  = __attribute__((ext_vector_type(8))) unsigned short;  // 16B staging
using f32x4  = __attribute__((ext_vector_type(4))) float;
using f32x4v = __attribute__((ext_vector_type(4))) float;

__device__ inline unsigned short f2bf(float f) {
  unsigned int u = __builtin_bit_cast(unsigned int, f);
  return (unsigned short)((u + 0x7fffu + ((u >> 16) & 1u)) >> 16);  // RNE
}

#define MFMA16(a, b, c) __builtin_amdgcn_mfma_f32_16x16x32_bf16((a), (b), (c), 0, 0, 0)

// LDS-visibility-only barrier: drains lgkmcnt but NOT vmcnt, so register-
// destined global prefetches stay in flight across the sync. All cross-thread
// communication in the attn loop is through LDS (P tiles), and each LDS
// buffer is recycled only after one further barrier.
__device__ __forceinline__ void lds_barrier() {
  __builtin_amdgcn_sched_barrier(0);
  asm volatile("s_waitcnt lgkmcnt(0)" ::: "memory");
  __builtin_amdgcn_sched_barrier(0);
  __builtin_amdgcn_s_barrier();
  __builtin_amdgcn_sched_barrier(0);
}

// Problem constants
#define LL 4096
#define NB 4
#define DD 512
#define KDIM 128

// ==========================================================================
// proj_qk (merged q+k): Out[b][l][128] = bf16( l2norm( X[l][b][:] @ Wk^T + bk ) )
// grid 512: bid&1 selects {query,key}; r0 = (bid>>1)*64 -> 2 blocks/CU.
// ==========================================================================
__global__ __launch_bounds__(256) void proj_qk_kernel(
    const float* __restrict__ Xq, const float* __restrict__ Xk,
    const float* __restrict__ Wk, const float* __restrict__ bk,
    unsigned short* __restrict__ Outq, unsigned short* __restrict__ Outk)
{
  __shared__ char smem[49152];                       // Xs 16KB | Ws 32KB
  char* Xs = smem;
  char* Ws = smem + 16384;

  const int tid = threadIdx.x;
  const int w = tid >> 6, lane = tid & 63, lr = lane & 15, g = lane >> 4;
  const int sel = blockIdx.x & 1;
  const float* X = sel ? Xk : Xq;
  unsigned short* Out = sel ? Outk : Outq;
  const int r0 = (blockIdx.x >> 1) * 64;

  f32x4 acc[8];
  #pragma unroll
  for (int nt = 0; nt < 8; ++nt) acc[nt] = f32x4{0.f, 0.f, 0.f, 0.f};

  for (int kc = 0; kc < 4; ++kc) {                   // K chunks of 128
    if (kc) __syncthreads();
    #pragma unroll
    for (int p = 0; p < 4; ++p) {
      int j = tid + p * 256;
      int row = j >> 4, e0 = (j & 15) * 8;
      const float* src = X + (size_t)(r0 + row) * DD + kc * 128 + e0;
      f32x4v f0 = *reinterpret_cast<const f32x4v*>(src);
      f32x4v f1 = *reinterpret_cast<const f32x4v*>(src + 4);
      u16x8 v;
      #pragma unroll
      for (int e = 0; e < 4; ++e) { v[e] = f2bf(f0[e]); v[e + 4] = f2bf(f1[e]); }
      *reinterpret_cast<u16x8*>(Xs + row * 256 + ((e0 * 2) ^ ((row & 7) << 4))) = v;
    }
    #pragma unroll
    for (int p = 0; p < 8; ++p) {
      int j = tid + p * 256;
      int n = j >> 4, e0 = (j & 15) * 8;
      const float* src = Wk + (size_t)n * DD + kc * 128 + e0;
      f32x4v f0 = *reinterpret_cast<const f32x4v*>(src);
      f32x4v f1 = *reinterpret_cast<const f32x4v*>(src + 4);
      u16x8 v;
      #pragma unroll
      for (int e = 0; e < 4; ++e) { v[e] = f2bf(f0[e]); v[e + 4] = f2bf(f1[e]); }
      *reinterpret_cast<u16x8*>(Ws + n * 256 + ((e0 * 2) ^ ((n & 7) << 4))) = v;
    }
    __syncthreads();
    const int arow = w * 16 + lr;
    #pragma unroll
    for (int ks = 0; ks < 4; ++ks) {
      int oa = (ks * 64 + g * 16) ^ ((arow & 7) << 4);
      bf16x8 a = *reinterpret_cast<const bf16x8*>(Xs + arow * 256 + oa);
      #pragma unroll
      for (int nt = 0; nt < 8; ++nt) {
        int n = nt * 16 + lr;
        int ob = (ks * 64 + g * 16) ^ ((n & 7) << 4);
        bf16x8 bb = *reinterpret_cast<const bf16x8*>(Ws + n * 256 + ob);
        acc[nt] = MFMA16(a, bb, acc[nt]);
      }
    }
  }

  float bias[8];
  #pragma unroll
  for (int nt = 0; nt < 8; ++nt) bias[nt] = bk[nt * 16 + lr];
  #pragma unroll
  for (int nt = 0; nt < 8; ++nt)
    #pragma unroll
    for (int i = 0; i < 4; ++i) acc[nt][i] += bias[nt];

  f32x4 ss = f32x4{0.f, 0.f, 0.f, 0.f};
  #pragma unroll
  for (int nt = 0; nt < 8; ++nt)
    #pragma unroll
    for (int i = 0; i < 4; ++i) ss[i] += acc[nt][i] * acc[nt][i];
  #pragma unroll
  for (int m = 1; m < 16; m <<= 1) {
    #pragma unroll
    for (int i = 0; i < 4; ++i) ss[i] += __shfl_xor(ss[i], m);
  }
  float inv[4];
  #pragma unroll
  for (int i = 0; i < 4; ++i) inv[i] = 1.0f / fmaxf(sqrtf(ss[i]), 1e-12f);

  #pragma unroll
  for (int nt = 0; nt < 8; ++nt) {
    int c = nt * 16 + lr;
    #pragma unroll
    for (int i = 0; i < 4; ++i) {
      int r = r0 + w * 16 + g * 4 + i;
      int l = r >> 2, b = r & 3;
      Out[((size_t)(b * LL + l)) * KDIM + c] = f2bf(acc[nt][i] * inv[i]);
    }
  }
}

// ==========================================================================
// proj_v: Vt[b][d][s] = bf16( value[s][b][:] @ Wv^T + bv )   (transposed store)
// ==========================================================================
__global__ __launch_bounds__(256) void proj_v_kernel(
    const float* __restrict__ X, const float* __restrict__ Wv,
    const float* __restrict__ bv, unsigned short* __restrict__ VtOut)
{
  __shared__ char smem[40960];
  char* Xs = smem;
  char* Ws = smem + 32768;

  const int tid = threadIdx.x;
  const int w = tid >> 6, lane = tid & 63, lr = lane & 15, g = lane >> 4;
  const int rb = blockIdx.x >> 3, nb = blockIdx.x & 7;
  const int r0 = rb * 256, d0 = nb * 64;

  f32x4 acc[4][4];
  #pragma unroll
  for (int rt = 0; rt < 4; ++rt)
    #pragma unroll
    for (int nt = 0; nt < 4; ++nt) acc[rt][nt] = f32x4{0.f, 0.f, 0.f, 0.f};

  for (int kc = 0; kc < 8; ++kc) {
    if (kc) __syncthreads();
    #pragma unroll
    for (int p = 0; p < 8; ++p) {
      int j = tid + p * 256;
      int row = j >> 3, e0 = (j & 7) * 8;
      const float* src = X + (size_t)(r0 + row) * DD + kc * 64 + e0;
      f32x4v f0 = *reinterpret_cast<const f32x4v*>(src);
      f32x4v f1 = *reinterpret_cast<const f32x4v*>(src + 4);
      u16x8 v;
      #pragma unroll
      for (int e = 0; e < 4; ++e) { v[e] = f2bf(f0[e]); v[e + 4] = f2bf(f1[e]); }
      *reinterpret_cast<u16x8*>(Xs + row * 128 + ((e0 * 2) ^ ((row & 7) << 4))) = v;
    }
    #pragma unroll
    for (int p = 0; p < 2; ++p) {
      int j = tid + p * 256;
      int n = j >> 3, e0 = (j & 7) * 8;
      const float* src = Wv + (size_t)(d0 + n) * DD + kc * 64 + e0;
      f32x4v f0 = *reinterpret_cast<const f32x4v*>(src);
      f32x4v f1 = *reinterpret_cast<const f32x4v*>(src + 4);
      u16x8 v;
      #pragma unroll
      for (int e = 0; e < 4; ++e) { v[e] = f2bf(f0[e]); v[e + 4] = f2bf(f1[e]); }
      *reinterpret_cast<u16x8*>(Ws + n * 128 + ((e0 * 2) ^ ((n & 7) << 4))) = v;
    }
    __syncthreads();
    #pragma unroll
    for (int ks = 0; ks < 2; ++ks) {
      bf16x8 a[4];
      #pragma unroll
      for (int rt = 0; rt < 4; ++rt) {
        int arow = w * 64 + rt * 16 + lr;
        a[rt] = *reinterpret_cast<const bf16x8*>(
            Xs + arow * 128 + ((ks * 64 + g * 16) ^ ((arow & 7) << 4)));
      }
      #pragma unroll
      for (int nt = 0; nt < 4; ++nt) {
        int n = nt * 16 + lr;
        bf16x8 bb = *reinterpret_cast<const bf16x8*>(
            Ws + n * 128 + ((ks * 64 + g * 16) ^ ((n & 7) << 4)));
        #pragma unroll
        for (int rt = 0; rt < 4; ++rt) acc[rt][nt] = MFMA16(a[rt], bb, acc[rt][nt]);
      }
    }
  }

  __syncthreads();
  float bias[4];
  #pragma unroll
  for (int nt = 0; nt < 4; ++nt) bias[nt] = bv[d0 + nt * 16 + lr];

  unsigned short* Ts = (unsigned short*)smem;
  #pragma unroll
  for (int rt = 0; rt < 4; ++rt)
    #pragma unroll
    for (int nt = 0; nt < 4; ++nt) {
      int dl = nt * 16 + lr;
      #pragma unroll
      for (int i = 0; i < 4; ++i) {
        int rl = w * 64 + rt * 16 + g * 4 + i;
        Ts[dl * 256 + (rl ^ ((dl & 31) << 1))] = f2bf(acc[rt][nt][i] + bias[nt]);
      }
    }
  __syncthreads();

  int bsel = tid >> 6, dl = tid & 63;
  int l0 = r0 >> 2;
  #pragma unroll
  for (int jj = 0; jj < 8; ++jj) {
    u16x8 v;
    #pragma unroll
    for (int e = 0; e < 8; ++e) {
      int rl = (jj * 8 + e) * 4 + bsel;
      v[e] = Ts[dl * 256 + (rl ^ ((dl & 31) << 1))];
    }
    *reinterpret_cast<u16x8*>(VtOut + ((size_t)(bsel * DD + d0 + dl)) * LL + l0 + jj * 8) = v;
  }
}

// ==========================================================================
// attn v4: 1024 thr / 16 waves (4 waves/SIMD), QBLK=64, KBLK=64.
// Wave w = (wq=w&3, ws=w>>2): S-subtile q[wq*16,+16) x s[ws*16,+16).
// K fragments loaded DIRECTLY from global (L1/L2-resident, no LDS staging).
// PV: all 64 q x d-slice [w*32,+32); V fragments global->reg, consumed after
// the barrier (full S+exp+Pwrite of latency cover, loads span the barrier).
// Only P lives in LDS (8KB double-buffered). One lds_barrier per step.
// ==========================================================================
#define QBLK 64
#define KBLK 64
#define NIT (LL / KBLK)          // 64 steps

struct AttnCtx {
  const unsigned short* Kp;
  const unsigned short* Vp;
  int lr, g, w, wq, ws;
};

// S phase for step t: K-fragment global loads, 4 MFMA, exp, P write.
__device__ __forceinline__ void s_phase(
    const AttnCtx& c, int t, char* pwr, const bf16x8 (&qf)[4],
    bf16x8 (&vreg)[2][2], float (&lsum)[4])
{
  const int s0 = t * KBLK;
  // ---- K fragments from global: s-row = ws*16+lr, k = kc*32+g*8 ----
  bf16x8 kb[4];
  #pragma unroll
  for (int kc = 0; kc < 4; ++kc)
    kb[kc] = *reinterpret_cast<const bf16x8*>(
        c.Kp + (size_t)(s0 + c.ws * 16 + c.lr) * KDIM + kc * 32 + c.g * 8);
  // ---- V fragments for PV(t): d = w*32+ch*16+lr, s = s0+sc*32+g*8 ----
  #pragma unroll
  for (int ch = 0; ch < 2; ++ch)
    #pragma unroll
    for (int sc = 0; sc < 2; ++sc)
      vreg[ch][sc] = *reinterpret_cast<const bf16x8*>(
          c.Vp + (size_t)(c.w * 32 + ch * 16 + c.lr) * LL + s0 + sc * 32 + c.g * 8);

  // ---- S: 16q x 16s ----
  f32x4 sacc = f32x4{0.f, 0.f, 0.f, 0.f};
  #pragma unroll
  for (int kc = 0; kc < 4; ++kc) sacc = MFMA16(qf[kc], kb[kc], sacc);

  // ---- softmax numerator (fixed max 31) + P write ----
  const int s = c.ws * 16 + c.lr;
  #pragma unroll
  for (int i = 0; i < 4; ++i) {
    float p = exp2f(fmaf(sacc[i], 43.280851f, -44.723546f));
    lsum[i] += p;
    int q = c.wq * 16 + c.g * 4 + i;
    *(unsigned short*)(pwr + q * 128 + ((s * 2) ^ ((q & 7) << 4))) = f2bf(p);
  }
}

// PV phase: all 64 q x this wave's 32-wide d slice, P from LDS, V from regs.
__device__ __forceinline__ void pv_phase(
    const AttnCtx& c, const char* prd, const bf16x8 (&vreg)[2][2],
    f32x4 (&acc)[4][2])
{
  #pragma unroll
  for (int qt = 0; qt < 4; ++qt) {
    int q = qt * 16 + c.lr;
    int swz = (q & 7) << 4;
    #pragma unroll
    for (int sc = 0; sc < 2; ++sc) {
      bf16x8 pa = *reinterpret_cast<const bf16x8*>(
          prd + q * 128 + ((sc * 64 + c.g * 16) ^ swz));
      acc[qt][0] = MFMA16(pa, vreg[0][sc], acc[qt][0]);
      acc[qt][1] = MFMA16(pa, vreg[1][sc], acc[qt][1]);
    }
  }
}

__global__ __launch_bounds__(1024) void attn_kernel(
    const unsigned short* __restrict__ Qn, const unsigned short* __restrict__ Kn,
    const unsigned short* __restrict__ Vt, float* __restrict__ Out)
{
  __shared__ char smem[17408];
  char* Ps0 = smem;                                  // [64 q][64 s] bf16, 8KB
  char* Ps1 = smem + 8192;
  float* Ls = (float*)(smem + 16384);                // [4 ws][64 q] partial sums

  const int tid = threadIdx.x;
  AttnCtx c;
  c.w = tid >> 6;
  const int lane = tid & 63;
  c.lr = lane & 15; c.g = lane >> 4;
  c.wq = c.w & 3; c.ws = c.w >> 2;

  // XCD-grouping swizzle: batch b -> XCD pair {2b,2b+1} (assumes rr dispatch)
  const int bid = blockIdx.x;
  const int b = (bid & 7) >> 1;
  const int tile = ((bid >> 3) << 1) | (bid & 1);
  const int q0 = tile * QBLK;

  c.Kp = Kn + (size_t)b * LL * KDIM;
  c.Vp = Vt + (size_t)b * DD * LL;

  // Q A-fragments (KD=128 -> 4 chunks of 32)
  bf16x8 qf[4];
  {
    const unsigned short* qp =
        Qn + ((size_t)(b * LL + q0 + c.wq * 16 + c.lr)) * KDIM + c.g * 8;
    #pragma unroll
    for (int kc = 0; kc < 4; ++kc)
      qf[kc] = *reinterpret_cast<const bf16x8*>(qp + kc * 32);
  }

  f32x4 acc[4][2];
  #pragma unroll
  for (int qt = 0; qt < 4; ++qt) {
    acc[qt][0] = f32x4{0.f, 0.f, 0.f, 0.f};
    acc[qt][1] = f32x4{0.f, 0.f, 0.f, 0.f};
  }
  float lsum[4] = {0.f, 0.f, 0.f, 0.f};
  bf16x8 vreg[2][2];

  // ---- prologue: step 0 S-phase ----
  s_phase(c, 0, Ps0, qf, vreg, lsum);
  lds_barrier();

  // ---- main loop ----
  for (int t = 1; t < NIT; ++t) {
    const char* prd = (t & 1) ? Ps0 : Ps1;   // written at step t-1
    char* pwr = (t & 1) ? Ps1 : Ps0;
    pv_phase(c, prd, vreg, acc);             // PV(t-1), consumes vreg
    s_phase(c, t, pwr, qf, vreg, lsum);      // refills vreg for PV(t)
    lds_barrier();
  }
  pv_phase(c, Ps1, vreg, acc);               // PV(63) (63&1 -> wrote Ps1)

  // ---- row-sum reduce: over lr lanes, then over ws via LDS ----
  #pragma unroll
  for (int m = 1; m < 16; m <<= 1) {
    #pragma unroll
    for (int i = 0; i < 4; ++i) lsum[i] += __shfl_xor(lsum[i], m);
  }
  if (c.lr == 0) {
    #pragma unroll
    for (int i = 0; i < 4; ++i)
      Ls[c.ws * 64 + c.wq * 16 + c.g * 4 + i] = lsum[i];
  }
  __syncthreads();

  // ---- scale by 1/l and store ----
  #pragma unroll
  for (int qt = 0; qt < 4; ++qt) {
    #pragma unroll
    for (int i = 0; i < 4; ++i) {
      int ql = qt * 16 + c.g * 4 + i;
      float l = Ls[ql] + Ls[64 + ql] + Ls[128 + ql] + Ls[192 + ql];
      float linv = 1.0f / l;
      int q = q0 + ql;
      #pragma unroll
      for (int ch = 0; ch < 2; ++ch) {
        int d = c.w * 32 + ch * 16 + c.lr;
        Out[((size_t)q * NB + b) * DD + d] = acc[qt][ch][i] * linv;
      }
    }
  }
}

// ==========================================================================
extern "C" void kernel_launch(void* const* d_in, const int* in_sizes, int n_in,
                              void* d_out, int out_size, void* d_ws, size_t ws_size,
                              hipStream_t stream) {
  const float* query = (const float*)d_in[0];
  const float* key   = (const float*)d_in[1];
  const float* value = (const float*)d_in[2];
  const float* WKw   = (const float*)d_in[3];
  const float* WKb   = (const float*)d_in[4];
  const float* WVw   = (const float*)d_in[5];
  const float* WVb   = (const float*)d_in[6];
  float* out = (float*)d_out;

  unsigned short* wqn = (unsigned short*)d_ws;            // [4][4096][128] bf16
  unsigned short* wkn = wqn + (size_t)NB * LL * KDIM;     // [4][4096][128] bf16
  unsigned short* vt  = wkn + (size_t)NB * LL * KDIM;     // [4][512][4096] bf16

  proj_qk_kernel<<<512, 256, 0, stream>>>(query, key, WKw, WKb, wqn, wkn);
  proj_v_kernel <<<512, 256, 0, stream>>>(value, WVw, WVb, vt);
  attn_kernel   <<<256, 1024, 0, stream>>>(wqn, wkn, vt, out);
}